// Round 8
// baseline (910.685 us; speedup 1.0000x reference)
//
#include <hip/hip_runtime.h>
#include <hip/hip_bf16.h>

// GCN 2-layer. With prescaled rows h'[v]=dinv[v]*h[v]:
//   agg[v] = dinv[v]*(h'[v] + sum_e h'[src_e]) + b
// CSR via bucket-binned counting sort (bucket-local rowptr/dinv).
// GEMMs via bf16 MFMA 16x16x32, epilogue scales by dinv and stores bf16.
// Aggregation: XCD-sliced, slice-major H[slice][node][16 dims] (32 B/node/slice,
//   3.2 MB/slice < 4 MB XCD L2; blockIdx%8 -> XCD).
// R2: traffic fixed (FETCH 639->57 MB), latency-bound. R3: exec-mask branches.
// R4: branch-free (170us). R5: zero-row + 32-bit addr + pipeline (118us, VALU-
//   issue-bound on structure: 90% dead slots, dword gathers, butterflies).
// R6: one node per 2 lanes (32 nodes/wave), dwordx4 gathers (2x16B = full row),
//   DEGREE-SORTED node order (counting sort) -> maxd ~= d, ~5% dead slots,
//   zero shuffles, epilogue amortized over 32 nodes.
//   (R6a: ext_vector u32x4 for nontemporal store — HIP uint4 class rejected.)
//   (R7: resubmit — infra failure, no counter evidence.)

#define D 128
#define BUKBITS 7          // 128 nodes per bucket
#define BUKSZ 128
#define MAXBUK 1024        // supports N <= 131072 (src < 2^25 packing)
#define SCHUNK 16384       // edges per scatter/hist block

#define NSLICE 8           // feature slices == XCDs
#define AGG_BLOCKS 2048    // 8 blocks/CU * 256 CUs co-resident at launch_bounds(256,8)
#define WAVES_PER_SLICE 1024  // (AGG_BLOCKS/NSLICE) * 4 waves

typedef __attribute__((ext_vector_type(8))) short short8;
typedef __attribute__((ext_vector_type(4))) float f32x4;
typedef __attribute__((ext_vector_type(2))) float f32x2;
typedef __attribute__((ext_vector_type(4))) uint u32x4;

static __device__ __forceinline__ ushort f2b(float f) {
    __hip_bfloat16 h = __float2bfloat16(f);
    return *reinterpret_cast<ushort*>(&h);
}

// ---------------- CSR build ----------------

__global__ __launch_bounds__(256) void k_bukhist(const int* __restrict__ dst, int* __restrict__ bukcnt,
                                                 int E, int nbuk) {
    __shared__ int lh[MAXBUK];
    for (int i = threadIdx.x; i < nbuk; i += 256) lh[i] = 0;
    __syncthreads();
    int start = blockIdx.x * SCHUNK;
    int end = min(E, start + SCHUNK);
    for (int e = start + threadIdx.x; e < end; e += 256)
        atomicAdd(&lh[dst[e] >> BUKBITS], 1);
    __syncthreads();
    for (int i = threadIdx.x; i < nbuk; i += 256)
        if (lh[i]) atomicAdd(&bukcnt[i], lh[i]);
}

__global__ __launch_bounds__(256) void k_bukscan(const int* __restrict__ bukcnt, int* __restrict__ bukbase,
                                                 int* __restrict__ gcur, int nbuk, int E) {
    __shared__ int vals[MAXBUK];
    __shared__ int tsum[256];
    int t = threadIdx.x;
    for (int i = t; i < MAXBUK; i += 256) vals[i] = (i < nbuk) ? bukcnt[i] : 0;
    __syncthreads();
    int o = t * 4;
    int s = vals[o] + vals[o + 1] + vals[o + 2] + vals[o + 3];
    tsum[t] = s;
    __syncthreads();
    for (int off = 1; off < 256; off <<= 1) {
        int v = (t >= off) ? tsum[t - off] : 0;
        __syncthreads();
        tsum[t] += v;
        __syncthreads();
    }
    int run = tsum[t] - s;
    for (int i = 0; i < 4; i++) {
        int idx = o + i;
        if (idx < nbuk) { bukbase[idx] = run; gcur[idx] = run; }
        run += vals[idx];
    }
    if (t == 0) bukbase[nbuk] = E;
}

// edges -> bucket-grouped tmp: (dstLow << 25) | src
__global__ __launch_bounds__(256) void k_scatter(const int* __restrict__ src, const int* __restrict__ dst,
                                                 int* __restrict__ gcur, uint* __restrict__ tmp,
                                                 int E, int nbuk) {
    __shared__ int lh[MAXBUK];
    __shared__ int lbase[MAXBUK];
    for (int i = threadIdx.x; i < nbuk; i += 256) lh[i] = 0;
    __syncthreads();
    int start = blockIdx.x * SCHUNK;
    int end = min(E, start + SCHUNK);
    for (int e = start + threadIdx.x; e < end; e += 256)
        atomicAdd(&lh[dst[e] >> BUKBITS], 1);
    __syncthreads();
    for (int i = threadIdx.x; i < nbuk; i += 256) {
        int c = lh[i];
        lbase[i] = c ? atomicAdd(&gcur[i], c) : 0;
        lh[i] = 0;
    }
    __syncthreads();
    for (int e = start + threadIdx.x; e < end; e += 256) {
        int s = src[e];
        int d = dst[e];
        int bk = d >> BUKBITS;
        int r = atomicAdd(&lh[bk], 1);
        tmp[lbase[bk] + r] = ((uint)(d & (BUKSZ - 1)) << 25) | (uint)s;
    }
}

// bucket-local: per-node count, LDS scan -> rowptr+dinv, place eord
__global__ __launch_bounds__(256) void k_fillC(const uint* __restrict__ tmp, const int* __restrict__ bukbase,
                                               int* __restrict__ eord, int* __restrict__ rowptr,
                                               float* __restrict__ dinv, int n, int nbuk) {
    __shared__ int cnt[BUKSZ];
    __shared__ int sc[BUKSZ];
    __shared__ int lrp[BUKSZ];
    int b = blockIdx.x;
    int node0 = b << BUKBITS;
    int nn = min(BUKSZ, n - node0);
    int e0 = bukbase[b], e1 = bukbase[b + 1];
    int t = threadIdx.x;
    if (t < BUKSZ) cnt[t] = 0;
    __syncthreads();
    for (int e = e0 + t; e < e1; e += 256)
        atomicAdd(&cnt[tmp[e] >> 25], 1);
    __syncthreads();
    int c0 = (t < BUKSZ) ? cnt[t] : 0;
    if (t < BUKSZ) sc[t] = c0;
    __syncthreads();
    for (int off = 1; off < BUKSZ; off <<= 1) {
        int v = (t < BUKSZ && t >= off) ? sc[t - off] : 0;
        __syncthreads();
        if (t < BUKSZ) sc[t] += v;
        __syncthreads();
    }
    if (t < BUKSZ) lrp[t] = e0 + sc[t] - c0;
    if (t < nn) {
        rowptr[node0 + t] = e0 + sc[t] - c0;
        dinv[node0 + t] = 1.0f / sqrtf((float)(c0 + 1));  // +1 self-loop
    }
    if (b == nbuk - 1 && t == 0) rowptr[n] = e1;
    __syncthreads();
    if (t < BUKSZ) cnt[t] = 0;
    __syncthreads();
    for (int e = e0 + t; e < e1; e += 256) {
        uint u = tmp[e];
        int dL = (int)(u >> 25);
        int s = (int)(u & 0x1FFFFFFu);
        int r = atomicAdd(&cnt[dL], 1);
        eord[lrp[dL] + r] = s;
    }
}

// ---------------- degree-binned node order (counting sort by degree) ----------------

__global__ __launch_bounds__(256) void k_deghist(const int* __restrict__ rowptr, int* __restrict__ dhist, int n) {
    __shared__ int lh[256];
    lh[threadIdx.x] = 0;
    __syncthreads();
    for (int v = blockIdx.x * 256 + threadIdx.x; v < n; v += gridDim.x * 256)
        atomicAdd(&lh[min(rowptr[v + 1] - rowptr[v], 255)], 1);
    __syncthreads();
    int c = lh[threadIdx.x];
    if (c) atomicAdd(&dhist[threadIdx.x], c);
}

__global__ __launch_bounds__(256) void k_degscan(const int* __restrict__ dhist, int* __restrict__ dcur) {
    __shared__ int sc[256];
    int t = threadIdx.x;
    int v = dhist[t];
    sc[t] = v;
    __syncthreads();
    for (int off = 1; off < 256; off <<= 1) {
        int u = (t >= off) ? sc[t - off] : 0;
        __syncthreads();
        sc[t] += u;
        __syncthreads();
    }
    dcur[t] = sc[t] - v;   // exclusive prefix
}

__global__ __launch_bounds__(256) void k_degscatter(const int* __restrict__ rowptr, int* __restrict__ dcur,
                                                    int* __restrict__ perm, int n) {
    __shared__ int lh[256];
    __shared__ int lbase[256];
    int t = threadIdx.x;
    lh[t] = 0;
    __syncthreads();
    for (int v = blockIdx.x * 256 + t; v < n; v += gridDim.x * 256)
        atomicAdd(&lh[min(rowptr[v + 1] - rowptr[v], 255)], 1);
    __syncthreads();
    {
        int c = lh[t];
        lbase[t] = c ? atomicAdd(&dcur[t], c) : 0;
        lh[t] = 0;
    }
    __syncthreads();
    for (int v = blockIdx.x * 256 + t; v < n; v += gridDim.x * 256) {
        int b = min(rowptr[v + 1] - rowptr[v], 255);
        int r = atomicAdd(&lh[b], 1);
        perm[lbase[b] + r] = v;
    }
}

// ---------------- init: zero-row n in both H buffers (all slices), eord pad = n ----------------
__global__ __launch_bounds__(256) void k_init(ushort* __restrict__ hbuf, ushort* __restrict__ act,
                                              int* __restrict__ eord, int n, int E) {
    int t = threadIdx.x;
    int nr = n + 1;
    if (t < 128) {                       // 8 slices * 16 ushorts
        int s = t >> 4, j = t & 15;
        hbuf[((size_t)s * nr + n) * 16 + j] = 0;
    } else {
        int tt = t - 128;
        int s = tt >> 4, j = tt & 15;
        act[((size_t)s * nr + n) * 16 + j] = 0;
    }
    if (t < 16) eord[E + t] = n;         // pad: dead slots gather the zero row
}

// ---------------- W prep: transpose + bf16 (Wt[n][k]) ----------------
__global__ __launch_bounds__(256) void k_prepW(const float* __restrict__ W1, const float* __restrict__ W2,
                                               ushort* __restrict__ Wt1, ushort* __restrict__ Wt2) {
    int i = blockIdx.x * 256 + threadIdx.x;
    if (i < 16384) {
        int kk = i >> 7, nn = i & 127;
        Wt1[nn * 128 + kk] = f2b(W1[i]);
        Wt2[nn * 128 + kk] = f2b(W2[i]);
    }
}

// ---------------- MFMA GEMM: H[slice][row][m] = bf16(dinv[row] * (X[row] @ W)) ----------------
// A fp32 row-major (layer1) or bf16 SLICE-MAJOR (layer2), slice stride = nr rows.
// MFMA layouts (verified): A[m=lane&15][k=quad*8+j]; B[k][n=lane&15];
// D col=lane&15, row=quad*4+r.  Output dim = t*16+m -> slice=t, within=m.
template <bool ABF16>
__global__ __launch_bounds__(256) void k_gemm(const void* __restrict__ Xv, const ushort* __restrict__ Wt,
                                              const float* __restrict__ dinv, ushort* __restrict__ Hb,
                                              int nrows, int nr) {
    const int wave = threadIdx.x >> 6;
    const int lane = threadIdx.x & 63;
    const int quad = lane >> 4;
    const int m = lane & 15;
    const int row0 = blockIdx.x * 64 + wave * 16;
    const int rowc = min(row0 + m, nrows - 1);

    f32x4 acc[8];
    #pragma unroll
    for (int t = 0; t < 8; t++) acc[t] = (f32x4){0.f, 0.f, 0.f, 0.f};

    #pragma unroll
    for (int ks = 0; ks < 4; ks++) {
        const int k0 = ks * 32 + quad * 8;
        short8 a;
        if (ABF16) {
            // slice-major: slice = k0>>4, within-slice offset = k0&15 (8-aligned, fits in slice)
            const ushort* p = (const ushort*)Xv + (size_t)(k0 >> 4) * nr * 16
                              + (size_t)rowc * 16 + (k0 & 15);
            a = *(const short8*)p;
        } else {
            const float* p = (const float*)Xv + (size_t)rowc * D + k0;
            float4 u0 = ((const float4*)p)[0];
            float4 u1 = ((const float4*)p)[1];
            a[0] = (short)f2b(u0.x); a[1] = (short)f2b(u0.y);
            a[2] = (short)f2b(u0.z); a[3] = (short)f2b(u0.w);
            a[4] = (short)f2b(u1.x); a[5] = (short)f2b(u1.y);
            a[6] = (short)f2b(u1.z); a[7] = (short)f2b(u1.w);
        }
        #pragma unroll
        for (int t = 0; t < 8; t++) {
            short8 b = *(const short8*)(Wt + ((t * 16 + m) * D + k0));
            acc[t] = __builtin_amdgcn_mfma_f32_16x16x32_bf16(a, b, acc[t], 0, 0, 0);
        }
    }
    #pragma unroll
    for (int r = 0; r < 4; r++) {
        int orow = row0 + quad * 4 + r;
        if (orow < nrows) {
            float dvv = dinv[orow];
            #pragma unroll
            for (int t = 0; t < 8; t++)
                Hb[(size_t)t * nr * 16 + (size_t)orow * 16 + m] = f2b(acc[t][r] * dvv);
        }
    }
}

// ---------------- XCD-sliced CSR aggregation: 1 node per 2 lanes ----------------
// Block b -> slice b%8 (-> XCD b%8). Wave: 32 degree-sorted nodes (perm order),
// lane = (node i = lane>>1, half = lane&1). Per iteration: one edge per node,
// dwordx4 gather (16B/lane, 2 lanes = full 32B row). Dead slots (k>=d) read
// eord pad -> zero row. No cross-lane reduction; epilogue on all 64 lanes.
template <bool RELU, bool OBF16>
__global__ __launch_bounds__(256, 8) void k_agg_slice(const ushort* __restrict__ Hb,
                                                      const float* __restrict__ dinv,
                                                      const int* __restrict__ rowptr,
                                                      const int* __restrict__ eord,
                                                      const int* __restrict__ perm,
                                                      const float* __restrict__ bias,
                                                      void* __restrict__ outp, int n, int E) {
    const int slice = blockIdx.x & (NSLICE - 1);
    const int blk = blockIdx.x >> 3;                      // block index within slice
    const int wid = (blk << 2) + (threadIdx.x >> 6);      // wave index within slice [0,1024)
    const int lane = threadIdx.x & 63;
    const int i = lane >> 1;                              // node slot 0..31
    const int half = lane & 1;                            // 16B half of the 32B row
    const int nr = n + 1;                                 // rows per slice (row n = zeros)
    const u32x4* __restrict__ Hs4 = (const u32x4*)((const uint*)Hb + (size_t)slice * nr * 8);
    const float4* __restrict__ b4 = (const float4*)bias;
    const float4 bb0 = b4[slice * 4 + half * 2];
    const float4 bb1 = b4[slice * 4 + half * 2 + 1];

    for (int v0 = wid * 32; v0 < n; v0 += WAVES_PER_SLICE * 32) {
        const int v = v0 + i;
        const int vc = min(v, n - 1);
        const int p  = __builtin_nontemporal_load(perm + vc);
        const int rp = __builtin_nontemporal_load(rowptr + p);
        const int d  = __builtin_nontemporal_load(rowptr + p + 1) - rp;

        int maxd = d;                                     // wave-max (halves share d)
        maxd = max(maxd, __shfl_xor(maxd, 2));
        maxd = max(maxd, __shfl_xor(maxd, 4));
        maxd = max(maxd, __shfl_xor(maxd, 8));
        maxd = max(maxd, __shfl_xor(maxd, 16));
        maxd = max(maxd, __shfl_xor(maxd, 32));
        maxd = __builtin_amdgcn_readfirstlane(maxd);

        float a0 = 0.f, a1 = 0.f, a2 = 0.f, a3 = 0.f;
        float a4 = 0.f, a5 = 0.f, a6 = 0.f, a7 = 0.f;

        if (maxd > 0) {
            uint ea = (0 < d) ? (uint)rp : (uint)E;       // eord[E..E+15] == n (zero row)
            int sidx = __builtin_nontemporal_load(eord + ea);
            for (int k = 1;; k++) {
                u32x4 hv = Hs4[((uint)sidx << 1) + (uint)half];
                const bool more = k < maxd;               // uniform branch
                int sidx2 = 0;
                if (more) {
                    uint ea2 = (k < d) ? (uint)(rp + k) : (uint)E;
                    sidx2 = __builtin_nontemporal_load(eord + ea2);   // in flight over consume
                }
                a0 += __uint_as_float(hv.x << 16);
                a1 += __uint_as_float(hv.x & 0xffff0000u);
                a2 += __uint_as_float(hv.y << 16);
                a3 += __uint_as_float(hv.y & 0xffff0000u);
                a4 += __uint_as_float(hv.z << 16);
                a5 += __uint_as_float(hv.z & 0xffff0000u);
                a6 += __uint_as_float(hv.w << 16);
                a7 += __uint_as_float(hv.w & 0xffff0000u);
                if (!more) break;
                sidx = sidx2;
            }
        }

        if (v < n) {
            u32x4 sv = Hs4[((uint)p << 1) + (uint)half];  // self-loop term (resident slice)
            a0 += __uint_as_float(sv.x << 16);
            a1 += __uint_as_float(sv.x & 0xffff0000u);
            a2 += __uint_as_float(sv.y << 16);
            a3 += __uint_as_float(sv.y & 0xffff0000u);
            a4 += __uint_as_float(sv.z << 16);
            a5 += __uint_as_float(sv.z & 0xffff0000u);
            a6 += __uint_as_float(sv.w << 16);
            a7 += __uint_as_float(sv.w & 0xffff0000u);
            float dv = __builtin_nontemporal_load(dinv + p);
            float r0 = fmaf(dv, a0, bb0.x), r1 = fmaf(dv, a1, bb0.y);
            float r2 = fmaf(dv, a2, bb0.z), r3 = fmaf(dv, a3, bb0.w);
            float r4 = fmaf(dv, a4, bb1.x), r5 = fmaf(dv, a5, bb1.y);
            float r6 = fmaf(dv, a6, bb1.z), r7 = fmaf(dv, a7, bb1.w);
            if (RELU) {
                r0 = fmaxf(r0, 0.f); r1 = fmaxf(r1, 0.f); r2 = fmaxf(r2, 0.f); r3 = fmaxf(r3, 0.f);
                r4 = fmaxf(r4, 0.f); r5 = fmaxf(r5, 0.f); r6 = fmaxf(r6, 0.f); r7 = fmaxf(r7, 0.f);
            }
            if (OBF16) {
                u32x4 wv;
                wv.x = ((uint)f2b(r1) << 16) | (uint)f2b(r0);
                wv.y = ((uint)f2b(r3) << 16) | (uint)f2b(r2);
                wv.z = ((uint)f2b(r5) << 16) | (uint)f2b(r4);
                wv.w = ((uint)f2b(r7) << 16) | (uint)f2b(r6);
                __builtin_nontemporal_store(wv,
                    (u32x4*)outp + (size_t)slice * nr * 2 + ((size_t)p << 1) + half);
            } else {
                float* po = (float*)outp + (size_t)p * D + slice * 16 + half * 8;
                __builtin_nontemporal_store((f32x4){r0, r1, r2, r3}, (f32x4*)po);
                __builtin_nontemporal_store((f32x4){r4, r5, r6, r7}, (f32x4*)(po + 4));
            }
        }
    }
}

// ---------------- launcher ----------------

static inline size_t alignup(size_t x) { return (x + 511) & ~(size_t)511; }

extern "C" void kernel_launch(void* const* d_in, const int* in_sizes, int n_in,
                              void* d_out, int out_size, void* d_ws, size_t ws_size,
                              hipStream_t stream) {
    const float* x  = (const float*)d_in[0];
    const int* eidx = (const int*)d_in[1];   // [2,E]: src row, dst row (int32)
    const float* W1 = (const float*)d_in[2];
    const float* b1 = (const float*)d_in[3];
    const float* W2 = (const float*)d_in[4];
    const float* b2 = (const float*)d_in[5];
    float* out = (float*)d_out;

    const int N = in_sizes[0] / D;
    const int E = in_sizes[1] / 2;
    const int NR = N + 1;                     // rows per slice incl. zero row
    const int* src = eidx;
    const int* dst = eidx + E;
    const int nbuk = (N + BUKSZ - 1) >> BUKBITS;   // 782

    // workspace
    char* ws = (char*)d_ws;
    size_t off = 0;
    int* bukcnt = (int*)(ws + off);   off = alignup(off + (size_t)MAXBUK * 4);
    int* bukbase = (int*)(ws + off);  off = alignup(off + (size_t)(MAXBUK + 1) * 4);
    int* gcur   = (int*)(ws + off);   off = alignup(off + (size_t)MAXBUK * 4);
    int* rowptr = (int*)(ws + off);   off = alignup(off + (size_t)(N + 1) * 4);
    float* dinv = (float*)(ws + off); off = alignup(off + (size_t)N * 4);
    int* eord   = (int*)(ws + off);   off = alignup(off + (size_t)(E + 16) * 4);
    int* dhist  = (int*)(ws + off);   off = alignup(off + 256 * 4);
    int* dcur   = (int*)(ws + off);   off = alignup(off + 256 * 4);
    int* perm   = (int*)(ws + off);   off = alignup(off + (size_t)N * 4);
    ushort* hbuf = (ushort*)(ws + off); off = alignup(off + (size_t)NR * D * 2);
    ushort* act  = (ushort*)(ws + off); off = alignup(off + (size_t)NR * D * 2);
    ushort* Wt1 = (ushort*)(ws + off); off = alignup(off + 16384 * 2);
    ushort* Wt2 = (ushort*)(ws + off); off = alignup(off + 16384 * 2);
    uint* tmp = (uint*)hbuf;  // E uints (6.4 MB) alias hbuf; dead before k_init/gemm1 writes
    (void)ws_size;

    const int nT = 256;
    const int gChunk = (E + SCHUNK - 1) / SCHUNK;   // 98

    hipMemsetAsync(bukcnt, 0, (size_t)MAXBUK * 4, stream);
    hipMemsetAsync(dhist, 0, 256 * 4, stream);
    k_prepW<<<64, nT, 0, stream>>>(W1, W2, Wt1, Wt2);
    k_bukhist<<<gChunk, nT, 0, stream>>>(dst, bukcnt, E, nbuk);
    k_bukscan<<<1, nT, 0, stream>>>(bukcnt, bukbase, gcur, nbuk, E);
    k_scatter<<<gChunk, nT, 0, stream>>>(src, dst, gcur, tmp, E, nbuk);
    k_fillC<<<nbuk, nT, 0, stream>>>(tmp, bukbase, eord, rowptr, dinv, N, nbuk);
    // degree-sorted node order (needs rowptr)
    k_deghist<<<64, nT, 0, stream>>>(rowptr, dhist, N);
    k_degscan<<<1, nT, 0, stream>>>(dhist, dcur);
    k_degscatter<<<64, nT, 0, stream>>>(rowptr, dcur, perm, N);
    k_init<<<1, nT, 0, stream>>>(hbuf, act, eord, N, E);   // after fillC: tmp (alias) dead

    const int gGemm = (N + 63) / 64;

    // layer 1: hbuf = bf16(dinv*(x @ W1)) slice-major; act(bf16 slice-major) = relu(agg + b1)
    k_gemm<false><<<gGemm, nT, 0, stream>>>((const void*)x, Wt1, dinv, hbuf, N, NR);
    k_agg_slice<true, true><<<AGG_BLOCKS, nT, 0, stream>>>(hbuf, dinv, rowptr, eord, perm, b1, (void*)act, N, E);

    // layer 2: hbuf = bf16(dinv*(act @ W2)) slice-major; out(fp32 row-major) = agg + b2
    k_gemm<true><<<gGemm, nT, 0, stream>>>((const void*)act, Wt2, dinv, hbuf, N, NR);
    k_agg_slice<false, false><<<AGG_BLOCKS, nT, 0, stream>>>(hbuf, dinv, rowptr, eord, perm, b2, (void*)out, N, E);
}

// Round 9
// 688.313 us; speedup vs baseline: 1.3231x; 1.3231x over previous
//
#include <hip/hip_runtime.h>
#include <hip/hip_bf16.h>

// GCN 2-layer. With prescaled rows h'[v]=dinv[v]*h[v]:
//   agg[v] = dinv[v]*(h'[v] + sum_e h'[src_e]) + b
// CSR via bucket-binned counting sort (bucket-local rowptr/dinv).
// GEMMs via bf16 MFMA 16x16x32, epilogue scales by dinv and stores bf16.
// Aggregation: XCD-sliced, slice-major H[slice][node][16 dims] (32 B/node/slice,
//   3.2 MB/slice < 4 MB XCD L2; blockIdx%8 -> XCD), degree-sorted node perm.
// R5 (118us): 16-slot groups, 8 gathers in flight -> worked but VALU-fat.
// R8 (332us): serial 1-edge/iter walk -> eord NT line-thrash (FETCH 632MB) +
//   MLP=1 (VALUBusy 4.7%). Schedule was wrong, not the topology.
// R9: chunked slot ownership: per 16-slot chunk, lane owns 8 slots; 8 coalesced
//   NT eord loads (consumed at once, no cross-iter line reuse) + 16 independent
//   16B gathers in flight; per-lane acc[16]; one cross-lane merge per node.

#define D 128
#define BUKBITS 7          // 128 nodes per bucket
#define BUKSZ 128
#define MAXBUK 1024        // supports N <= 131072 (src < 2^25 packing)
#define SCHUNK 16384       // edges per scatter/hist block

#define NSLICE 8           // feature slices == XCDs
#define AGG_BLOCKS 1024    // 4 blocks/CU * 256 CUs co-resident at launch_bounds(256,4)
#define WAVES_PER_SLICE 512   // (AGG_BLOCKS/NSLICE) * 4 waves

typedef __attribute__((ext_vector_type(8))) short short8;
typedef __attribute__((ext_vector_type(4))) float f32x4;
typedef __attribute__((ext_vector_type(2))) float f32x2;
typedef __attribute__((ext_vector_type(4))) uint u32x4;

static __device__ __forceinline__ ushort f2b(float f) {
    __hip_bfloat16 h = __float2bfloat16(f);
    return *reinterpret_cast<ushort*>(&h);
}
static __device__ __forceinline__ float blo(uint u) { return __uint_as_float(u << 16); }
static __device__ __forceinline__ float bhi(uint u) { return __uint_as_float(u & 0xffff0000u); }

// ---------------- CSR build ----------------

__global__ __launch_bounds__(256) void k_bukhist(const int* __restrict__ dst, int* __restrict__ bukcnt,
                                                 int E, int nbuk) {
    __shared__ int lh[MAXBUK];
    for (int i = threadIdx.x; i < nbuk; i += 256) lh[i] = 0;
    __syncthreads();
    int start = blockIdx.x * SCHUNK;
    int end = min(E, start + SCHUNK);
    for (int e = start + threadIdx.x; e < end; e += 256)
        atomicAdd(&lh[dst[e] >> BUKBITS], 1);
    __syncthreads();
    for (int i = threadIdx.x; i < nbuk; i += 256)
        if (lh[i]) atomicAdd(&bukcnt[i], lh[i]);
}

__global__ __launch_bounds__(256) void k_bukscan(const int* __restrict__ bukcnt, int* __restrict__ bukbase,
                                                 int* __restrict__ gcur, int nbuk, int E) {
    __shared__ int vals[MAXBUK];
    __shared__ int tsum[256];
    int t = threadIdx.x;
    for (int i = t; i < MAXBUK; i += 256) vals[i] = (i < nbuk) ? bukcnt[i] : 0;
    __syncthreads();
    int o = t * 4;
    int s = vals[o] + vals[o + 1] + vals[o + 2] + vals[o + 3];
    tsum[t] = s;
    __syncthreads();
    for (int off = 1; off < 256; off <<= 1) {
        int v = (t >= off) ? tsum[t - off] : 0;
        __syncthreads();
        tsum[t] += v;
        __syncthreads();
    }
    int run = tsum[t] - s;
    for (int i = 0; i < 4; i++) {
        int idx = o + i;
        if (idx < nbuk) { bukbase[idx] = run; gcur[idx] = run; }
        run += vals[idx];
    }
    if (t == 0) bukbase[nbuk] = E;
}

// edges -> bucket-grouped tmp: (dstLow << 25) | src
__global__ __launch_bounds__(256) void k_scatter(const int* __restrict__ src, const int* __restrict__ dst,
                                                 int* __restrict__ gcur, uint* __restrict__ tmp,
                                                 int E, int nbuk) {
    __shared__ int lh[MAXBUK];
    __shared__ int lbase[MAXBUK];
    for (int i = threadIdx.x; i < nbuk; i += 256) lh[i] = 0;
    __syncthreads();
    int start = blockIdx.x * SCHUNK;
    int end = min(E, start + SCHUNK);
    for (int e = start + threadIdx.x; e < end; e += 256)
        atomicAdd(&lh[dst[e] >> BUKBITS], 1);
    __syncthreads();
    for (int i = threadIdx.x; i < nbuk; i += 256) {
        int c = lh[i];
        lbase[i] = c ? atomicAdd(&gcur[i], c) : 0;
        lh[i] = 0;
    }
    __syncthreads();
    for (int e = start + threadIdx.x; e < end; e += 256) {
        int s = src[e];
        int d = dst[e];
        int bk = d >> BUKBITS;
        int r = atomicAdd(&lh[bk], 1);
        tmp[lbase[bk] + r] = ((uint)(d & (BUKSZ - 1)) << 25) | (uint)s;
    }
}

// bucket-local: per-node count, LDS scan -> rowptr+dinv, place eord
__global__ __launch_bounds__(256) void k_fillC(const uint* __restrict__ tmp, const int* __restrict__ bukbase,
                                               int* __restrict__ eord, int* __restrict__ rowptr,
                                               float* __restrict__ dinv, int n, int nbuk) {
    __shared__ int cnt[BUKSZ];
    __shared__ int sc[BUKSZ];
    __shared__ int lrp[BUKSZ];
    int b = blockIdx.x;
    int node0 = b << BUKBITS;
    int nn = min(BUKSZ, n - node0);
    int e0 = bukbase[b], e1 = bukbase[b + 1];
    int t = threadIdx.x;
    if (t < BUKSZ) cnt[t] = 0;
    __syncthreads();
    for (int e = e0 + t; e < e1; e += 256)
        atomicAdd(&cnt[tmp[e] >> 25], 1);
    __syncthreads();
    int c0 = (t < BUKSZ) ? cnt[t] : 0;
    if (t < BUKSZ) sc[t] = c0;
    __syncthreads();
    for (int off = 1; off < BUKSZ; off <<= 1) {
        int v = (t < BUKSZ && t >= off) ? sc[t - off] : 0;
        __syncthreads();
        if (t < BUKSZ) sc[t] += v;
        __syncthreads();
    }
    if (t < BUKSZ) lrp[t] = e0 + sc[t] - c0;
    if (t < nn) {
        rowptr[node0 + t] = e0 + sc[t] - c0;
        dinv[node0 + t] = 1.0f / sqrtf((float)(c0 + 1));  // +1 self-loop
    }
    if (b == nbuk - 1 && t == 0) rowptr[n] = e1;
    __syncthreads();
    if (t < BUKSZ) cnt[t] = 0;
    __syncthreads();
    for (int e = e0 + t; e < e1; e += 256) {
        uint u = tmp[e];
        int dL = (int)(u >> 25);
        int s = (int)(u & 0x1FFFFFFu);
        int r = atomicAdd(&cnt[dL], 1);
        eord[lrp[dL] + r] = s;
    }
}

// ---------------- degree-binned node order (counting sort by degree) ----------------

__global__ __launch_bounds__(256) void k_deghist(const int* __restrict__ rowptr, int* __restrict__ dhist, int n) {
    __shared__ int lh[256];
    lh[threadIdx.x] = 0;
    __syncthreads();
    for (int v = blockIdx.x * 256 + threadIdx.x; v < n; v += gridDim.x * 256)
        atomicAdd(&lh[min(rowptr[v + 1] - rowptr[v], 255)], 1);
    __syncthreads();
    int c = lh[threadIdx.x];
    if (c) atomicAdd(&dhist[threadIdx.x], c);
}

__global__ __launch_bounds__(256) void k_degscan(const int* __restrict__ dhist, int* __restrict__ dcur) {
    __shared__ int sc[256];
    int t = threadIdx.x;
    int v = dhist[t];
    sc[t] = v;
    __syncthreads();
    for (int off = 1; off < 256; off <<= 1) {
        int u = (t >= off) ? sc[t - off] : 0;
        __syncthreads();
        sc[t] += u;
        __syncthreads();
    }
    dcur[t] = sc[t] - v;   // exclusive prefix
}

__global__ __launch_bounds__(256) void k_degscatter(const int* __restrict__ rowptr, int* __restrict__ dcur,
                                                    int* __restrict__ perm, int n) {
    __shared__ int lh[256];
    __shared__ int lbase[256];
    int t = threadIdx.x;
    lh[t] = 0;
    __syncthreads();
    for (int v = blockIdx.x * 256 + t; v < n; v += gridDim.x * 256)
        atomicAdd(&lh[min(rowptr[v + 1] - rowptr[v], 255)], 1);
    __syncthreads();
    {
        int c = lh[t];
        lbase[t] = c ? atomicAdd(&dcur[t], c) : 0;
        lh[t] = 0;
    }
    __syncthreads();
    for (int v = blockIdx.x * 256 + t; v < n; v += gridDim.x * 256) {
        int b = min(rowptr[v + 1] - rowptr[v], 255);
        int r = atomicAdd(&lh[b], 1);
        perm[lbase[b] + r] = v;
    }
}

// ---------------- init: zero-row n in both H buffers (all slices), eord pad = n ----------------
__global__ __launch_bounds__(256) void k_init(ushort* __restrict__ hbuf, ushort* __restrict__ act,
                                              int* __restrict__ eord, int n, int E) {
    int t = threadIdx.x;
    int nr = n + 1;
    if (t < 128) {                       // 8 slices * 16 ushorts
        int s = t >> 4, j = t & 15;
        hbuf[((size_t)s * nr + n) * 16 + j] = 0;
    } else {
        int tt = t - 128;
        int s = tt >> 4, j = tt & 15;
        act[((size_t)s * nr + n) * 16 + j] = 0;
    }
    if (t < 16) eord[E + t] = n;         // pad: dead slots gather the zero row
}

// ---------------- W prep: transpose + bf16 (Wt[n][k]) ----------------
__global__ __launch_bounds__(256) void k_prepW(const float* __restrict__ W1, const float* __restrict__ W2,
                                               ushort* __restrict__ Wt1, ushort* __restrict__ Wt2) {
    int i = blockIdx.x * 256 + threadIdx.x;
    if (i < 16384) {
        int kk = i >> 7, nn = i & 127;
        Wt1[nn * 128 + kk] = f2b(W1[i]);
        Wt2[nn * 128 + kk] = f2b(W2[i]);
    }
}

// ---------------- MFMA GEMM: H[slice][row][m] = bf16(dinv[row] * (X[row] @ W)) ----------------
// A fp32 row-major (layer1) or bf16 SLICE-MAJOR (layer2), slice stride = nr rows.
// MFMA layouts (verified): A[m=lane&15][k=quad*8+j]; B[k][n=lane&15];
// D col=lane&15, row=quad*4+r.  Output dim = t*16+m -> slice=t, within=m.
template <bool ABF16>
__global__ __launch_bounds__(256) void k_gemm(const void* __restrict__ Xv, const ushort* __restrict__ Wt,
                                              const float* __restrict__ dinv, ushort* __restrict__ Hb,
                                              int nrows, int nr) {
    const int wave = threadIdx.x >> 6;
    const int lane = threadIdx.x & 63;
    const int quad = lane >> 4;
    const int m = lane & 15;
    const int row0 = blockIdx.x * 64 + wave * 16;
    const int rowc = min(row0 + m, nrows - 1);

    f32x4 acc[8];
    #pragma unroll
    for (int t = 0; t < 8; t++) acc[t] = (f32x4){0.f, 0.f, 0.f, 0.f};

    #pragma unroll
    for (int ks = 0; ks < 4; ks++) {
        const int k0 = ks * 32 + quad * 8;
        short8 a;
        if (ABF16) {
            // slice-major: slice = k0>>4, within-slice offset = k0&15 (8-aligned, fits in slice)
            const ushort* p = (const ushort*)Xv + (size_t)(k0 >> 4) * nr * 16
                              + (size_t)rowc * 16 + (k0 & 15);
            a = *(const short8*)p;
        } else {
            const float* p = (const float*)Xv + (size_t)rowc * D + k0;
            float4 u0 = ((const float4*)p)[0];
            float4 u1 = ((const float4*)p)[1];
            a[0] = (short)f2b(u0.x); a[1] = (short)f2b(u0.y);
            a[2] = (short)f2b(u0.z); a[3] = (short)f2b(u0.w);
            a[4] = (short)f2b(u1.x); a[5] = (short)f2b(u1.y);
            a[6] = (short)f2b(u1.z); a[7] = (short)f2b(u1.w);
        }
        #pragma unroll
        for (int t = 0; t < 8; t++) {
            short8 b = *(const short8*)(Wt + ((t * 16 + m) * D + k0));
            acc[t] = __builtin_amdgcn_mfma_f32_16x16x32_bf16(a, b, acc[t], 0, 0, 0);
        }
    }
    #pragma unroll
    for (int r = 0; r < 4; r++) {
        int orow = row0 + quad * 4 + r;
        if (orow < nrows) {
            float dvv = dinv[orow];
            #pragma unroll
            for (int t = 0; t < 8; t++)
                Hb[(size_t)t * nr * 16 + (size_t)orow * 16 + m] = f2b(acc[t][r] * dvv);
        }
    }
}

// ---------------- XCD-sliced CSR aggregation: 1 node per 2 lanes, 16-slot chunks ----------------
// Block b -> slice b%8 (-> XCD b%8). Wave: 32 degree-sorted nodes (perm order).
// Per chunk of 16 edge slots: lane (half) owns slots half*8+j -> 8 coalesced NT
// eord loads (pair covers 64B consecutive, consumed at once) + 16 independent
// 16B gathers (full 32B row per owned slot) in flight. Dead slots clamp to
// eord[E] -> zero row n. Per-lane acc[16]; cross-lane pair merge per node.
template <bool RELU, bool OBF16>
__global__ __launch_bounds__(256, 4) void k_agg_slice(const ushort* __restrict__ Hb,
                                                      const float* __restrict__ dinv,
                                                      const int* __restrict__ rowptr,
                                                      const int* __restrict__ eord,
                                                      const int* __restrict__ perm,
                                                      const float* __restrict__ bias,
                                                      void* __restrict__ outp, int n, int E) {
    const int slice = blockIdx.x & (NSLICE - 1);
    const int blk = blockIdx.x >> 3;                      // block index within slice
    const int wid = (blk << 2) + (threadIdx.x >> 6);      // wave index within slice [0,512)
    const int lane = threadIdx.x & 63;
    const int i = lane >> 1;                              // node slot 0..31
    const int half = lane & 1;                            // slot-group / 16B half owner
    const int nr = n + 1;                                 // rows per slice (row n = zeros)
    const u32x4* __restrict__ Hs4 = (const u32x4*)((const uint*)Hb + (size_t)slice * nr * 8);
    const float4* __restrict__ b4 = (const float4*)bias;
    const float4 bb0 = b4[slice * 4 + half * 2];          // dims slice*16+half*8 .. +3
    const float4 bb1 = b4[slice * 4 + half * 2 + 1];      // dims slice*16+half*8+4 .. +7

    for (int v0 = wid * 32; v0 < n; v0 += WAVES_PER_SLICE * 32) {
        const int v = v0 + i;
        const int vc = min(v, n - 1);
        const int p  = perm[vc];
        const int rp = rowptr[p];
        const int d  = rowptr[p + 1] - rp;

        int maxd = d;                                     // wave-max (halves share d)
        maxd = max(maxd, __shfl_xor(maxd, 2));
        maxd = max(maxd, __shfl_xor(maxd, 4));
        maxd = max(maxd, __shfl_xor(maxd, 8));
        maxd = max(maxd, __shfl_xor(maxd, 16));
        maxd = max(maxd, __shfl_xor(maxd, 32));
        maxd = __builtin_amdgcn_readfirstlane(maxd);

        float acc[16];
        #pragma unroll
        for (int j = 0; j < 16; j++) acc[j] = 0.f;

        for (int kc = 0; kc < maxd; kc += 16) {
            // 8 owned slots: s = kc + half*8 + j; clamped to pad (-> zero row)
            int idx[8];
            #pragma unroll
            for (int j = 0; j < 8; j++) {
                int s = kc + half * 8 + j;
                uint ea = (s < d) ? (uint)(rp + s) : (uint)E;
                idx[j] = __builtin_nontemporal_load(eord + ea);
            }
            // 16 independent gathers (full 32B row per slot), all in flight
            u32x4 g0[8], g1[8];
            #pragma unroll
            for (int j = 0; j < 8; j++) {
                uint base = (uint)idx[j] << 1;
                g0[j] = Hs4[base];
                g1[j] = Hs4[base + 1];
            }
            #pragma unroll
            for (int j = 0; j < 8; j++) {
                acc[0]  += blo(g0[j].x); acc[1]  += bhi(g0[j].x);
                acc[2]  += blo(g0[j].y); acc[3]  += bhi(g0[j].y);
                acc[4]  += blo(g0[j].z); acc[5]  += bhi(g0[j].z);
                acc[6]  += blo(g0[j].w); acc[7]  += bhi(g0[j].w);
                acc[8]  += blo(g1[j].x); acc[9]  += bhi(g1[j].x);
                acc[10] += blo(g1[j].y); acc[11] += bhi(g1[j].y);
                acc[12] += blo(g1[j].z); acc[13] += bhi(g1[j].z);
                acc[14] += blo(g1[j].w); acc[15] += bhi(g1[j].w);
            }
        }

        // merge the two lanes of the node: dims 0-7 (lo) and 8-15 (hi)
        float out[8];
        #pragma unroll
        for (int j = 0; j < 8; j++) {
            float lo_t = acc[j]     + __shfl_xor(acc[j], 1);
            float hi_t = acc[8 + j] + __shfl_xor(acc[8 + j], 1);
            out[j] = half ? hi_t : lo_t;
        }

        if (v < n) {
            u32x4 sv = Hs4[((uint)p << 1) + (uint)half];  // self-loop term (resident slice)
            out[0] += blo(sv.x); out[1] += bhi(sv.x);
            out[2] += blo(sv.y); out[3] += bhi(sv.y);
            out[4] += blo(sv.z); out[5] += bhi(sv.z);
            out[6] += blo(sv.w); out[7] += bhi(sv.w);
            float dv = __builtin_nontemporal_load(dinv + p);
            float r0 = fmaf(dv, out[0], bb0.x), r1 = fmaf(dv, out[1], bb0.y);
            float r2 = fmaf(dv, out[2], bb0.z), r3 = fmaf(dv, out[3], bb0.w);
            float r4 = fmaf(dv, out[4], bb1.x), r5 = fmaf(dv, out[5], bb1.y);
            float r6 = fmaf(dv, out[6], bb1.z), r7 = fmaf(dv, out[7], bb1.w);
            if (RELU) {
                r0 = fmaxf(r0, 0.f); r1 = fmaxf(r1, 0.f); r2 = fmaxf(r2, 0.f); r3 = fmaxf(r3, 0.f);
                r4 = fmaxf(r4, 0.f); r5 = fmaxf(r5, 0.f); r6 = fmaxf(r6, 0.f); r7 = fmaxf(r7, 0.f);
            }
            if (OBF16) {
                u32x4 wv;
                wv.x = ((uint)f2b(r1) << 16) | (uint)f2b(r0);
                wv.y = ((uint)f2b(r3) << 16) | (uint)f2b(r2);
                wv.z = ((uint)f2b(r5) << 16) | (uint)f2b(r4);
                wv.w = ((uint)f2b(r7) << 16) | (uint)f2b(r6);
                __builtin_nontemporal_store(wv,
                    (u32x4*)outp + (size_t)slice * nr * 2 + ((size_t)p << 1) + half);
            } else {
                float* po = (float*)outp + (size_t)p * D + slice * 16 + half * 8;
                __builtin_nontemporal_store((f32x4){r0, r1, r2, r3}, (f32x4*)po);
                __builtin_nontemporal_store((f32x4){r4, r5, r6, r7}, (f32x4*)(po + 4));
            }
        }
    }
}

// ---------------- launcher ----------------

static inline size_t alignup(size_t x) { return (x + 511) & ~(size_t)511; }

extern "C" void kernel_launch(void* const* d_in, const int* in_sizes, int n_in,
                              void* d_out, int out_size, void* d_ws, size_t ws_size,
                              hipStream_t stream) {
    const float* x  = (const float*)d_in[0];
    const int* eidx = (const int*)d_in[1];   // [2,E]: src row, dst row (int32)
    const float* W1 = (const float*)d_in[2];
    const float* b1 = (const float*)d_in[3];
    const float* W2 = (const float*)d_in[4];
    const float* b2 = (const float*)d_in[5];
    float* out = (float*)d_out;

    const int N = in_sizes[0] / D;
    const int E = in_sizes[1] / 2;
    const int NR = N + 1;                     // rows per slice incl. zero row
    const int* src = eidx;
    const int* dst = eidx + E;
    const int nbuk = (N + BUKSZ - 1) >> BUKBITS;   // 782

    // workspace
    char* ws = (char*)d_ws;
    size_t off = 0;
    int* bukcnt = (int*)(ws + off);   off = alignup(off + (size_t)MAXBUK * 4);
    int* bukbase = (int*)(ws + off);  off = alignup(off + (size_t)(MAXBUK + 1) * 4);
    int* gcur   = (int*)(ws + off);   off = alignup(off + (size_t)MAXBUK * 4);
    int* rowptr = (int*)(ws + off);   off = alignup(off + (size_t)(N + 1) * 4);
    float* dinv = (float*)(ws + off); off = alignup(off + (size_t)N * 4);
    int* eord   = (int*)(ws + off);   off = alignup(off + (size_t)(E + 16) * 4);
    int* dhist  = (int*)(ws + off);   off = alignup(off + 256 * 4);
    int* dcur   = (int*)(ws + off);   off = alignup(off + 256 * 4);
    int* perm   = (int*)(ws + off);   off = alignup(off + (size_t)N * 4);
    ushort* hbuf = (ushort*)(ws + off); off = alignup(off + (size_t)NR * D * 2);
    ushort* act  = (ushort*)(ws + off); off = alignup(off + (size_t)NR * D * 2);
    ushort* Wt1 = (ushort*)(ws + off); off = alignup(off + 16384 * 2);
    ushort* Wt2 = (ushort*)(ws + off); off = alignup(off + 16384 * 2);
    uint* tmp = (uint*)hbuf;  // E uints (6.4 MB) alias hbuf; dead before k_init/gemm1 writes
    (void)ws_size;

    const int nT = 256;
    const int gChunk = (E + SCHUNK - 1) / SCHUNK;   // 98

    hipMemsetAsync(bukcnt, 0, (size_t)MAXBUK * 4, stream);
    hipMemsetAsync(dhist, 0, 256 * 4, stream);
    k_prepW<<<64, nT, 0, stream>>>(W1, W2, Wt1, Wt2);
    k_bukhist<<<gChunk, nT, 0, stream>>>(dst, bukcnt, E, nbuk);
    k_bukscan<<<1, nT, 0, stream>>>(bukcnt, bukbase, gcur, nbuk, E);
    k_scatter<<<gChunk, nT, 0, stream>>>(src, dst, gcur, tmp, E, nbuk);
    k_fillC<<<nbuk, nT, 0, stream>>>(tmp, bukbase, eord, rowptr, dinv, N, nbuk);
    // degree-sorted node order (needs rowptr)
    k_deghist<<<64, nT, 0, stream>>>(rowptr, dhist, N);
    k_degscan<<<1, nT, 0, stream>>>(dhist, dcur);
    k_degscatter<<<64, nT, 0, stream>>>(rowptr, dcur, perm, N);
    k_init<<<1, nT, 0, stream>>>(hbuf, act, eord, N, E);   // after fillC: tmp (alias) dead

    const int gGemm = (N + 63) / 64;

    // layer 1: hbuf = bf16(dinv*(x @ W1)) slice-major; act(bf16 slice-major) = relu(agg + b1)
    k_gemm<false><<<gGemm, nT, 0, stream>>>((const void*)x, Wt1, dinv, hbuf, N, NR);
    k_agg_slice<true, true><<<AGG_BLOCKS, nT, 0, stream>>>(hbuf, dinv, rowptr, eord, perm, b1, (void*)act, N, E);

    // layer 2: hbuf = bf16(dinv*(act @ W2)) slice-major; out(fp32 row-major) = agg + b2
    k_gemm<true><<<gGemm, nT, 0, stream>>>((const void*)act, Wt2, dinv, hbuf, N, NR);
    k_agg_slice<false, false><<<AGG_BLOCKS, nT, 0, stream>>>(hbuf, dinv, rowptr, eord, perm, b2, (void*)out, N, E);
}